// Round 1
// baseline (10317.487 us; speedup 1.0000x reference)
//
#include <hip/hip_runtime.h>

#define T_LEN 4096
#define E_DIM 1024
#define H_DIM 512
#define NT_DIM 32
#define NG 3072          // 2 * 3H columns of gi
#define G_WG 16          // workgroups per direction in recurrence

typedef __attribute__((ext_vector_type(8))) short bf16x8;
typedef __attribute__((ext_vector_type(4))) float f32x4;

__device__ inline unsigned short f2bf(float f) {
    unsigned int u = __float_as_uint(f);
    unsigned int r = (u + 0x7fffu + ((u >> 16) & 1u)) >> 16;
    return (unsigned short)r;
}

// ---------- kernel 1: embedding gather + bf16 cast  (xb[t][e]) ----------
__global__ void embed_cast(const int* __restrict__ sent, const float* __restrict__ emb,
                           unsigned short* __restrict__ xb) {
    int t = blockIdx.x;
    int row = sent[t];
    const float4* src = (const float4*)(emb + (size_t)row * E_DIM);
    ushort4* dst = (ushort4*)(xb + (size_t)t * E_DIM);
    float4 v = src[threadIdx.x];
    ushort4 o;
    o.x = f2bf(v.x); o.y = f2bf(v.y); o.z = f2bf(v.z); o.w = f2bf(v.w);
    dst[threadIdx.x] = o;
}

// ---------- kernel 2: W_ih (f then b) -> bf16, concat rows ----------
__global__ void wcast(const float* __restrict__ wf, const float* __restrict__ wb_,
                      unsigned short* __restrict__ w) {
    int r = blockIdx.x;  // 0..3071
    const float* src = (r < 1536) ? (wf + (size_t)r * E_DIM) : (wb_ + (size_t)(r - 1536) * E_DIM);
    const float4* s4 = (const float4*)src;
    ushort4* dst = (ushort4*)(w + (size_t)r * E_DIM);
    float4 v = s4[threadIdx.x];
    ushort4 o;
    o.x = f2bf(v.x); o.y = f2bf(v.y); o.z = f2bf(v.z); o.w = f2bf(v.w);
    dst[threadIdx.x] = o;
}

// ---------- kernel 3: gi = xb @ wb^T + b_ih   [4096 x 3072] fp32 ----------
#define LDST 40   // LDS row stride (bf16 elems): 80B -> 2-way bank alias (free), 16B aligned
__global__ __launch_bounds__(256) void gi_gemm(const unsigned short* __restrict__ xb,
                                               const unsigned short* __restrict__ wb,
                                               const float* __restrict__ bihf,
                                               const float* __restrict__ bihb,
                                               float* __restrict__ gi) {
    __shared__ __align__(16) unsigned short As[64 * LDST];
    __shared__ __align__(16) unsigned short Bs[64 * LDST];
    int tile_m = (blockIdx.x % 64) * 64;
    int tile_n = (blockIdx.x / 64) * 64;
    int tid = threadIdx.x;
    int lane = tid & 63, wv = tid >> 6;
    int quad = lane >> 4, r15 = lane & 15;
    int srow = tid >> 2, sseg = tid & 3;

    f32x4 acc[4] = {};
    for (int kb = 0; kb < E_DIM; kb += 32) {
        uint4 a = *(const uint4*)(xb + (size_t)(tile_m + srow) * E_DIM + kb + sseg * 8);
        uint4 b = *(const uint4*)(wb + (size_t)(tile_n + srow) * E_DIM + kb + sseg * 8);
        *(uint4*)&As[srow * LDST + sseg * 8] = a;
        *(uint4*)&Bs[srow * LDST + sseg * 8] = b;
        __syncthreads();
        bf16x8 af = *(bf16x8*)&As[(wv * 16 + r15) * LDST + quad * 8];
#pragma unroll
        for (int nt = 0; nt < 4; nt++) {
            bf16x8 bf = *(bf16x8*)&Bs[(nt * 16 + r15) * LDST + quad * 8];
            acc[nt] = __builtin_amdgcn_mfma_f32_16x16x32_bf16(af, bf, acc[nt], 0, 0, 0);
        }
        __syncthreads();
    }
#pragma unroll
    for (int nt = 0; nt < 4; nt++) {
        int gn = tile_n + nt * 16 + r15;
        float bias = (gn < 1536) ? bihf[gn] : bihb[gn - 1536];
#pragma unroll
        for (int rg = 0; rg < 4; rg++) {
            int gm = tile_m + wv * 16 + quad * 4 + rg;
            gi[(size_t)gm * NG + gn] = acc[nt][rg] + bias;
        }
    }
}

// ---------- kernel 4: persistent bidirectional GRU recurrence ----------
// grid = 32 blocks x 512 threads. blocks 0..15 = fwd, 16..31 = bwd.
// Each WG owns 32 h-outputs; thread (kp = tid&31, q = tid>>5) holds
// W_hh rows {kg, kg+512, kg+1024}, cols [32q, 32q+32) in 96 VGPRs.
__global__ __launch_bounds__(512, 2) void gru_rec(
    const float* __restrict__ whhf, const float* __restrict__ bhhf,
    const float* __restrict__ whhb, const float* __restrict__ bhhb,
    const float* __restrict__ gi, float* __restrict__ hf, float* __restrict__ hb,
    int* __restrict__ cnt) {
    int wgid = blockIdx.x;
    int dir = (wgid >= G_WG) ? 1 : 0;
    int g = wgid - dir * G_WG;
    const float* whh = dir ? whhb : whhf;
    const float* bhh = dir ? bhhb : bhhf;
    float* hbuf = dir ? hb : hf;
    int* c = cnt + dir * T_LEN;

    int tid = threadIdx.x;
    int kp = tid & 31;
    int q = tid >> 5;            // 0..15
    int kg = g * 32 + kp;        // global h index of this thread's rows
    int wave = tid >> 6;         // 0..7
    int lane = tid & 63;

    // persistent weights in registers
    float4 wr[8], wz[8], wn[8];
    {
        const float4* pr_ = (const float4*)(whh + (size_t)kg * H_DIM + q * 32);
        const float4* pz_ = (const float4*)(whh + (size_t)(kg + 512) * H_DIM + q * 32);
        const float4* pn_ = (const float4*)(whh + (size_t)(kg + 1024) * H_DIM + q * 32);
#pragma unroll
        for (int i = 0; i < 8; i++) { wr[i] = pr_[i]; wz[i] = pz_[i]; wn[i] = pn_[i]; }
    }
    float bias_r = 0.f, bias_z = 0.f, bias_n = 0.f, h_own = 0.f;
    if (tid < 32) {
        bias_r = bhh[kg]; bias_z = bhh[kg + 512]; bias_n = bhh[kg + 1024];
    }
    __shared__ float part[3][8][32];

    for (int s = 0; s < T_LEN; s++) {
        int row = dir ? (T_LEN - 1 - s) : s;
        float gir = 0.f, giz = 0.f, gin = 0.f;
        if (tid < 32) {
            const float* gp = gi + (size_t)row * NG + dir * 1536 + kg;
            gir = gp[0]; giz = gp[512]; gin = gp[1024];
        }
        float pr = 0.f, pz = 0.f, pn = 0.f;
        if (s > 0) {
            int prow = dir ? (T_LEN - s) : (s - 1);
            const float4* hp = (const float4*)(hbuf + (size_t)prow * H_DIM + q * 32);
            float4 h4[8];
#pragma unroll
            for (int i = 0; i < 8; i++) h4[i] = hp[i];
#pragma unroll
            for (int i = 0; i < 8; i++) {
                pr += wr[i].x * h4[i].x + wr[i].y * h4[i].y + wr[i].z * h4[i].z + wr[i].w * h4[i].w;
                pz += wz[i].x * h4[i].x + wz[i].y * h4[i].y + wz[i].z * h4[i].z + wz[i].w * h4[i].w;
                pn += wn[i].x * h4[i].x + wn[i].y * h4[i].y + wn[i].z * h4[i].z + wn[i].w * h4[i].w;
            }
        }
        // q-pair reduce within wave (lanes l and l^32 share kp)
        pr += __shfl_xor(pr, 32);
        pz += __shfl_xor(pz, 32);
        pn += __shfl_xor(pn, 32);
        if (lane < 32) {
            part[0][wave][kp] = pr; part[1][wave][kp] = pz; part[2][wave][kp] = pn;
        }
        __syncthreads();
        if (tid < 32) {
            float sr = bias_r, sz = bias_z, sn = bias_n;
#pragma unroll
            for (int w = 0; w < 8; w++) {
                sr += part[0][w][kp]; sz += part[1][w][kp]; sn += part[2][w][kp];
            }
            float rr = 1.f / (1.f + __expf(-(gir + sr)));
            float zz = 1.f / (1.f + __expf(-(giz + sz)));
            float a = gin + rr * sn;
            a = fminf(20.f, fmaxf(-20.f, a));
            float e = __expf(-2.f * a);
            float nn = (1.f - e) / (1.f + e);
            float hnew = (1.f - zz) * nn + zz * h_own;
            h_own = hnew;
            hbuf[(size_t)row * H_DIM + kg] = hnew;
        }
        __syncthreads();  // all 32 stores complete (vmcnt drained) before arrive
        if (tid == 0) {
            __hip_atomic_fetch_add(&c[s], 1, __ATOMIC_RELEASE, __HIP_MEMORY_SCOPE_AGENT);
            while (__hip_atomic_load(&c[s], __ATOMIC_RELAXED, __HIP_MEMORY_SCOPE_AGENT) < G_WG)
                __builtin_amdgcn_s_sleep(1);
            (void)__hip_atomic_load(&c[s], __ATOMIC_ACQUIRE, __HIP_MEMORY_SCOPE_AGENT);
        }
        __syncthreads();
    }
}

// ---------- kernel 5: out = [hf|hb] @ W_out^T   [4096 x 32] ----------
__global__ __launch_bounds__(256) void out_gemm(const float* __restrict__ hf,
                                                const float* __restrict__ hb,
                                                const float* __restrict__ wout,
                                                float* __restrict__ out) {
    __shared__ __align__(16) float ls[8][1028];  // +4 pad: r8 groups hit different banks
    int t0 = blockIdx.x * 8;
    int tid = threadIdx.x;
#pragma unroll
    for (int i = 0; i < 8; i++) {
        int col = tid * 4;
        float4 v = (col < 512) ? *(const float4*)(hf + (size_t)(t0 + i) * H_DIM + col)
                               : *(const float4*)(hb + (size_t)(t0 + i) * H_DIM + (col - 512));
        *(float4*)&ls[i][col] = v;
    }
    __syncthreads();
    int r8 = tid >> 5, gg = tid & 31;
    const float4* wp = (const float4*)(wout + (size_t)gg * 1024);
    float sum = 0.f;
#pragma unroll 8
    for (int j = 0; j < 256; j++) {
        float4 w = wp[j];
        float4 h = *(const float4*)&ls[r8][j * 4];
        sum += w.x * h.x + w.y * h.y + w.z * h.z + w.w * h.w;
    }
    out[(size_t)(t0 + r8) * NT_DIM + gg] = sum;
}

extern "C" void kernel_launch(void* const* d_in, const int* in_sizes, int n_in,
                              void* d_out, int out_size, void* d_ws, size_t ws_size,
                              hipStream_t stream) {
    const int*   sent = (const int*)d_in[0];
    const float* emb  = (const float*)d_in[1];
    const float* wihf = (const float*)d_in[2];
    const float* whhf = (const float*)d_in[3];
    const float* bihf = (const float*)d_in[4];
    const float* bhhf = (const float*)d_in[5];
    const float* wihb = (const float*)d_in[6];
    const float* whhb = (const float*)d_in[7];
    const float* bihb = (const float*)d_in[8];
    const float* bhhb = (const float*)d_in[9];
    const float* wout = (const float*)d_in[10];

    char* ws = (char*)d_ws;
    float*          gi  = (float*)(ws);                       // 4096*3072*4 = 50331648
    unsigned short* xb  = (unsigned short*)(ws + 50331648);   // 4096*1024*2 = 8388608
    unsigned short* wb  = (unsigned short*)(ws + 58720256);   // 3072*1024*2 = 6291456
    float*          hf  = (float*)(ws + 65011712);            // 4096*512*4  = 8388608
    float*          hb  = (float*)(ws + 73400320);            // 8388608
    int*            cnt = (int*)(ws + 81788928);              // 2*4096*4    = 32768
    float*          out = (float*)d_out;

    hipMemsetAsync(cnt, 0, 2 * T_LEN * sizeof(int), stream);
    embed_cast<<<T_LEN, 256, 0, stream>>>(sent, emb, xb);
    wcast<<<NG, 256, 0, stream>>>(wihf, wihb, wb);
    gi_gemm<<<64 * 48, 256, 0, stream>>>(xb, wb, bihf, bihb, gi);
    gru_rec<<<2 * G_WG, 512, 0, stream>>>(whhf, bhhf, whhb, bhhb, gi, hf, hb, cnt);
    out_gemm<<<T_LEN / 8, 256, 0, stream>>>(hf, hb, wout, out);
}

// Round 2
// 7053.394 us; speedup vs baseline: 1.4628x; 1.4628x over previous
//
#include <hip/hip_runtime.h>

#define T_LEN 4096
#define E_DIM 1024
#define H_DIM 512
#define NT_DIM 32
#define NG 3072          // 2 * 3H columns of gi
#define G_DIR 64         // workgroups per direction in recurrence
#define OPW 8            // h-outputs per workgroup (512 / 64)

typedef __attribute__((ext_vector_type(8))) short bf16x8;
typedef __attribute__((ext_vector_type(4))) float f32x4;
typedef unsigned long long ull;

__device__ inline unsigned short f2bf(float f) {
    unsigned int u = __float_as_uint(f);
    unsigned int r = (u + 0x7fffu + ((u >> 16) & 1u)) >> 16;
    return (unsigned short)r;
}
__device__ inline float bf2f(unsigned short u) {
    return __uint_as_float(((unsigned int)u) << 16);
}
__device__ inline ull packhs(float v, unsigned tag) {
    return (ull)__float_as_uint(v) | ((ull)tag << 32);
}

// ---------- kernel 1: embedding gather + bf16 cast  (xb[t][e]) ----------
__global__ void embed_cast(const int* __restrict__ sent, const float* __restrict__ emb,
                           unsigned short* __restrict__ xb) {
    int t = blockIdx.x;
    int row = sent[t];
    const float4* src = (const float4*)(emb + (size_t)row * E_DIM);
    ushort4* dst = (ushort4*)(xb + (size_t)t * E_DIM);
    float4 v = src[threadIdx.x];
    ushort4 o;
    o.x = f2bf(v.x); o.y = f2bf(v.y); o.z = f2bf(v.z); o.w = f2bf(v.w);
    dst[threadIdx.x] = o;
}

// ---------- kernel 2: W_ih (f then b) -> bf16, concat rows ----------
__global__ void wcast(const float* __restrict__ wf, const float* __restrict__ wb_,
                      unsigned short* __restrict__ w) {
    int r = blockIdx.x;  // 0..3071
    const float* src = (r < 1536) ? (wf + (size_t)r * E_DIM) : (wb_ + (size_t)(r - 1536) * E_DIM);
    const float4* s4 = (const float4*)src;
    ushort4* dst = (ushort4*)(w + (size_t)r * E_DIM);
    float4 v = s4[threadIdx.x];
    ushort4 o;
    o.x = f2bf(v.x); o.y = f2bf(v.y); o.z = f2bf(v.z); o.w = f2bf(v.w);
    dst[threadIdx.x] = o;
}

// ---------- kernel 3: gi = xb @ wb^T + b_ih   [4096 x 3072] -> bf16 ----------
#define LDST 40
__global__ __launch_bounds__(256) void gi_gemm(const unsigned short* __restrict__ xb,
                                               const unsigned short* __restrict__ wb,
                                               const float* __restrict__ bihf,
                                               const float* __restrict__ bihb,
                                               unsigned short* __restrict__ gi) {
    __shared__ __align__(16) unsigned short As[64 * LDST];
    __shared__ __align__(16) unsigned short Bs[64 * LDST];
    int tile_m = (blockIdx.x % 64) * 64;
    int tile_n = (blockIdx.x / 64) * 64;
    int tid = threadIdx.x;
    int lane = tid & 63, wv = tid >> 6;
    int quad = lane >> 4, r15 = lane & 15;
    int srow = tid >> 2, sseg = tid & 3;

    f32x4 acc[4] = {};
    for (int kb = 0; kb < E_DIM; kb += 32) {
        uint4 a = *(const uint4*)(xb + (size_t)(tile_m + srow) * E_DIM + kb + sseg * 8);
        uint4 b = *(const uint4*)(wb + (size_t)(tile_n + srow) * E_DIM + kb + sseg * 8);
        *(uint4*)&As[srow * LDST + sseg * 8] = a;
        *(uint4*)&Bs[srow * LDST + sseg * 8] = b;
        __syncthreads();
        bf16x8 af = *(bf16x8*)&As[(wv * 16 + r15) * LDST + quad * 8];
#pragma unroll
        for (int nt = 0; nt < 4; nt++) {
            bf16x8 bf = *(bf16x8*)&Bs[(nt * 16 + r15) * LDST + quad * 8];
            acc[nt] = __builtin_amdgcn_mfma_f32_16x16x32_bf16(af, bf, acc[nt], 0, 0, 0);
        }
        __syncthreads();
    }
#pragma unroll
    for (int nt = 0; nt < 4; nt++) {
        int gn = tile_n + nt * 16 + r15;
        float bias = (gn < 1536) ? bihf[gn] : bihb[gn - 1536];
#pragma unroll
        for (int rg = 0; rg < 4; rg++) {
            int gm = tile_m + wv * 16 + quad * 4 + rg;
            gi[(size_t)gm * NG + gn] = f2bf(acc[nt][rg] + bias);
        }
    }
}

// ---------- kernel 4: persistent bidirectional GRU recurrence ----------
// 128 WGs x 512 threads; blocks [0,64) = fwd, [64,128) = bwd.
// h exchange via self-synchronizing {f32,tag} 8B slots at agent scope
// (relaxed atomics -> coherence point; NO release/acquire, L2 stays warm).
// Each WG owns 8 h-outputs. Thread (kp=tid&7, q=tid>>3) holds W_hh rows
// {kg, kg+512, kg+1024}, cols [8q, 8q+8) = 24 persistent VGPRs.
__global__ __launch_bounds__(512) void gru_rec(
    const float* __restrict__ whhf, const float* __restrict__ bhhf,
    const float* __restrict__ whhb, const float* __restrict__ bhhb,
    const unsigned short* __restrict__ gi, ull* __restrict__ hxf, ull* __restrict__ hxb) {
    int wgid = blockIdx.x;
    int dir = wgid >> 6;
    int g = wgid & 63;
    const float* whh = dir ? whhb : whhf;
    const float* bhh = dir ? bhhb : bhhf;
    ull* hx = dir ? hxb : hxf;

    int tid = threadIdx.x;
    int kp = tid & 7;
    int q = tid >> 3;            // 0..63
    int kg = g * OPW + kp;
    int wave = tid >> 6;
    int lane = tid & 63;

    // persistent weights
    float4 wr[2], wz[2], wn[2];
    {
        const float4* pr_ = (const float4*)(whh + (size_t)kg * H_DIM + q * 8);
        const float4* pz_ = (const float4*)(whh + (size_t)(kg + 512) * H_DIM + q * 8);
        const float4* pn_ = (const float4*)(whh + (size_t)(kg + 1024) * H_DIM + q * 8);
        wr[0] = pr_[0]; wr[1] = pr_[1];
        wz[0] = pz_[0]; wz[1] = pz_[1];
        wn[0] = pn_[0]; wn[1] = pn_[1];
    }
    float bias_r = 0.f, bias_z = 0.f, bias_n = 0.f, h_own = 0.f;
    int kg0 = g * OPW + tid;     // valid for tid < 8
    if (tid < OPW) {
        bias_r = bhh[kg0]; bias_z = bhh[kg0 + 512]; bias_n = bhh[kg0 + 1024];
    }

    __shared__ float hsh[512];
    __shared__ float part[3][8][OPW];

    for (int s = 0; s < T_LEN; s++) {
        int row = dir ? (T_LEN - 1 - s) : s;
        // issue gi loads early (normal loads, L2-cached — no invalidation anywhere)
        float gir = 0.f, giz = 0.f, gin = 0.f;
        if (tid < OPW) {
            const unsigned short* gp = gi + (size_t)row * NG + dir * 1536 + kg0;
            gir = bf2f(gp[0]); giz = bf2f(gp[512]); gin = bf2f(gp[1024]);
        }
        // fetch h_{s-1}: poll own slot (tag == s means value from step s-1)
        float hv = 0.f;
        if (s > 0) {
            int prow = dir ? (T_LEN - s) : (s - 1);
            const ull* slot = hx + (size_t)prow * H_DIM + tid;
            ull p;
            do {
                p = __hip_atomic_load(slot, __ATOMIC_RELAXED, __HIP_MEMORY_SCOPE_AGENT);
            } while ((unsigned)(p >> 32) != (unsigned)s);
            hv = __uint_as_float((unsigned)p);
        }
        hsh[tid] = hv;
        __syncthreads();

        float4 h0 = *(const float4*)&hsh[q * 8];
        float4 h1 = *(const float4*)&hsh[q * 8 + 4];
        float pr, pz, pn;
        pr  = wr[0].x * h0.x + wr[0].y * h0.y + wr[0].z * h0.z + wr[0].w * h0.w
            + wr[1].x * h1.x + wr[1].y * h1.y + wr[1].z * h1.z + wr[1].w * h1.w;
        pz  = wz[0].x * h0.x + wz[0].y * h0.y + wz[0].z * h0.z + wz[0].w * h0.w
            + wz[1].x * h1.x + wz[1].y * h1.y + wz[1].z * h1.z + wz[1].w * h1.w;
        pn  = wn[0].x * h0.x + wn[0].y * h0.y + wn[0].z * h0.z + wn[0].w * h0.w
            + wn[1].x * h1.x + wn[1].y * h1.y + wn[1].z * h1.z + wn[1].w * h1.w;
        // reduce across q&7 within the wave (lane bits 3..5)
        pr += __shfl_xor(pr, 8);  pz += __shfl_xor(pz, 8);  pn += __shfl_xor(pn, 8);
        pr += __shfl_xor(pr, 16); pz += __shfl_xor(pz, 16); pn += __shfl_xor(pn, 16);
        pr += __shfl_xor(pr, 32); pz += __shfl_xor(pz, 32); pn += __shfl_xor(pn, 32);
        if (lane < OPW) {
            part[0][wave][lane] = pr; part[1][wave][lane] = pz; part[2][wave][lane] = pn;
        }
        __syncthreads();

        if (tid < OPW) {
            float sr = bias_r, sz = bias_z, sn = bias_n;
#pragma unroll
            for (int w = 0; w < 8; w++) {
                sr += part[0][w][tid]; sz += part[1][w][tid]; sn += part[2][w][tid];
            }
            float rr = 1.f / (1.f + __expf(-(gir + sr)));
            float zz = 1.f / (1.f + __expf(-(giz + sz)));
            float a = gin + rr * sn;
            a = fminf(20.f, fmaxf(-20.f, a));
            float e = __expf(-2.f * a);
            float nn = (1.f - e) / (1.f + e);
            float hnew = (1.f - zz) * nn + zz * h_own;
            h_own = hnew;
            __hip_atomic_store(hx + (size_t)row * H_DIM + kg0, packhs(hnew, (unsigned)(s + 1)),
                               __ATOMIC_RELAXED, __HIP_MEMORY_SCOPE_AGENT);
        }
        // hsh[step s] reads all happened before the part-store sync above;
        // next iteration's hsh write comes after each thread passes it. Safe.
    }
}

// ---------- kernel 5: out = [hf|hb] @ W_out^T   [4096 x 32] ----------
__global__ __launch_bounds__(256) void out_gemm(const ull* __restrict__ hxf,
                                                const ull* __restrict__ hxb,
                                                const float* __restrict__ wout,
                                                float* __restrict__ out) {
    __shared__ __align__(16) float ls[8][1028];
    int t0 = blockIdx.x * 8;
    int tid = threadIdx.x;
#pragma unroll
    for (int i = 0; i < 8; i++) {
        int col = tid * 4;   // 0..1020
        const ull* src = (col < 512) ? (hxf + (size_t)(t0 + i) * H_DIM + col)
                                     : (hxb + (size_t)(t0 + i) * H_DIM + (col - 512));
        ull s0 = src[0], s1 = src[1], s2 = src[2], s3 = src[3];
        ls[i][col + 0] = __uint_as_float((unsigned)s0);
        ls[i][col + 1] = __uint_as_float((unsigned)s1);
        ls[i][col + 2] = __uint_as_float((unsigned)s2);
        ls[i][col + 3] = __uint_as_float((unsigned)s3);
    }
    __syncthreads();
    int r8 = tid >> 5, gg = tid & 31;
    const float4* wp = (const float4*)(wout + (size_t)gg * 1024);
    float sum = 0.f;
#pragma unroll 8
    for (int j = 0; j < 256; j++) {
        float4 w = wp[j];
        float4 h = *(const float4*)&ls[r8][j * 4];
        sum += w.x * h.x + w.y * h.y + w.z * h.z + w.w * h.w;
    }
    out[(size_t)(t0 + r8) * NT_DIM + gg] = sum;
}

extern "C" void kernel_launch(void* const* d_in, const int* in_sizes, int n_in,
                              void* d_out, int out_size, void* d_ws, size_t ws_size,
                              hipStream_t stream) {
    const int*   sent = (const int*)d_in[0];
    const float* emb  = (const float*)d_in[1];
    const float* wihf = (const float*)d_in[2];
    const float* whhf = (const float*)d_in[3];
    const float* bihf = (const float*)d_in[4];
    const float* bhhf = (const float*)d_in[5];
    const float* wihb = (const float*)d_in[6];
    const float* whhb = (const float*)d_in[7];
    const float* bihb = (const float*)d_in[8];
    const float* bhhb = (const float*)d_in[9];
    const float* wout = (const float*)d_in[10];

    char* ws = (char*)d_ws;
    unsigned short* gi  = (unsigned short*)(ws);              // 4096*3072*2 = 25165824
    unsigned short* xb  = (unsigned short*)(ws + 25165824);   // 4096*1024*2 =  8388608
    unsigned short* wb  = (unsigned short*)(ws + 33554432);   // 3072*1024*2 =  6291456
    ull*            hxf = (ull*)(ws + 39845888);              // 4096*512*8  = 16777216
    ull*            hxb = (ull*)(ws + 56623104);              // 16777216 (total 73400320)
    float*          out = (float*)d_out;

    embed_cast<<<T_LEN, 256, 0, stream>>>(sent, emb, xb);
    wcast<<<NG, 256, 0, stream>>>(wihf, wihb, wb);
    gi_gemm<<<64 * 48, 256, 0, stream>>>(xb, wb, bihf, bihb, gi);
    gru_rec<<<2 * G_DIR, 512, 0, stream>>>(whhf, bhhf, whhb, bhhb, gi, hxf, hxb);
    out_gemm<<<T_LEN / 8, 256, 0, stream>>>(hxf, hxb, wout, out);
}

// Round 3
// 6248.759 us; speedup vs baseline: 1.6511x; 1.1288x over previous
//
#include <hip/hip_runtime.h>

#define T_LEN 4096
#define E_DIM 1024
#define H_DIM 512
#define NT_DIM 32
#define NG 3072          // 2 * 3H columns of gi
#define G_DIR 64         // workgroups per direction in recurrence
#define OPW 8            // h-outputs per workgroup (512 / 64)

typedef __attribute__((ext_vector_type(8))) short bf16x8;
typedef __attribute__((ext_vector_type(4))) float f32x4;
typedef unsigned long long ull;

__device__ inline unsigned short f2bf(float f) {
    unsigned int u = __float_as_uint(f);
    unsigned int r = (u + 0x7fffu + ((u >> 16) & 1u)) >> 16;
    return (unsigned short)r;
}
__device__ inline float bf2f(unsigned short u) {
    return __uint_as_float(((unsigned int)u) << 16);
}
__device__ inline ull packhs(float v, unsigned tag) {
    return (ull)__float_as_uint(v) | ((ull)tag << 32);
}

// ---------- kernel 1: embedding gather + bf16 cast  (xb[t][e]) ----------
__global__ void embed_cast(const int* __restrict__ sent, const float* __restrict__ emb,
                           unsigned short* __restrict__ xb) {
    int t = blockIdx.x;
    int row = sent[t];
    const float4* src = (const float4*)(emb + (size_t)row * E_DIM);
    ushort4* dst = (ushort4*)(xb + (size_t)t * E_DIM);
    float4 v = src[threadIdx.x];
    ushort4 o;
    o.x = f2bf(v.x); o.y = f2bf(v.y); o.z = f2bf(v.z); o.w = f2bf(v.w);
    dst[threadIdx.x] = o;
}

// ---------- kernel 2: W_ih (f then b) -> bf16, concat rows ----------
__global__ void wcast(const float* __restrict__ wf, const float* __restrict__ wb_,
                      unsigned short* __restrict__ w) {
    int r = blockIdx.x;  // 0..3071
    const float* src = (r < 1536) ? (wf + (size_t)r * E_DIM) : (wb_ + (size_t)(r - 1536) * E_DIM);
    const float4* s4 = (const float4*)src;
    ushort4* dst = (ushort4*)(w + (size_t)r * E_DIM);
    float4 v = s4[threadIdx.x];
    ushort4 o;
    o.x = f2bf(v.x); o.y = f2bf(v.y); o.z = f2bf(v.z); o.w = f2bf(v.w);
    dst[threadIdx.x] = o;
}

// ---------- kernel 3: gi = xb @ wb^T + b_ih   [4096 x 3072] -> bf16 ----------
#define LDST 40
__global__ __launch_bounds__(256) void gi_gemm(const unsigned short* __restrict__ xb,
                                               const unsigned short* __restrict__ wb,
                                               const float* __restrict__ bihf,
                                               const float* __restrict__ bihb,
                                               unsigned short* __restrict__ gi) {
    __shared__ __align__(16) unsigned short As[64 * LDST];
    __shared__ __align__(16) unsigned short Bs[64 * LDST];
    int tile_m = (blockIdx.x % 64) * 64;
    int tile_n = (blockIdx.x / 64) * 64;
    int tid = threadIdx.x;
    int lane = tid & 63, wv = tid >> 6;
    int quad = lane >> 4, r15 = lane & 15;
    int srow = tid >> 2, sseg = tid & 3;

    f32x4 acc[4] = {};
    for (int kb = 0; kb < E_DIM; kb += 32) {
        uint4 a = *(const uint4*)(xb + (size_t)(tile_m + srow) * E_DIM + kb + sseg * 8);
        uint4 b = *(const uint4*)(wb + (size_t)(tile_n + srow) * E_DIM + kb + sseg * 8);
        *(uint4*)&As[srow * LDST + sseg * 8] = a;
        *(uint4*)&Bs[srow * LDST + sseg * 8] = b;
        __syncthreads();
        bf16x8 af = *(bf16x8*)&As[(wv * 16 + r15) * LDST + quad * 8];
#pragma unroll
        for (int nt = 0; nt < 4; nt++) {
            bf16x8 bf = *(bf16x8*)&Bs[(nt * 16 + r15) * LDST + quad * 8];
            acc[nt] = __builtin_amdgcn_mfma_f32_16x16x32_bf16(af, bf, acc[nt], 0, 0, 0);
        }
        __syncthreads();
    }
#pragma unroll
    for (int nt = 0; nt < 4; nt++) {
        int gn = tile_n + nt * 16 + r15;
        float bias = (gn < 1536) ? bihf[gn] : bihb[gn - 1536];
#pragma unroll
        for (int rg = 0; rg < 4; rg++) {
            int gm = tile_m + wv * 16 + quad * 4 + rg;
            gi[(size_t)gm * NG + gn] = f2bf(acc[nt][rg] + bias);
        }
    }
}

// ---------- kernel 4: persistent bidirectional GRU recurrence ----------
// 128 WGs x 512 threads; blocks [0,64) = fwd, [64,128) = bwd.
// h exchange: self-synchronizing {f32,tag} 8B slots, relaxed agent atomics.
// ONLY WAVE 0 of each WG touches global memory (poll / gi / h store) —
// waves 1-7 wait at __syncthreads, cutting concurrent poll streams 8x.
// Thread (kp=tid&7, q=tid>>3) holds W_hh rows {kg,kg+512,kg+1024},
// cols [8q, 8q+8) = 24 persistent VGPRs.
__global__ __launch_bounds__(512) void gru_rec(
    const float* __restrict__ whhf, const float* __restrict__ bhhf,
    const float* __restrict__ whhb, const float* __restrict__ bhhb,
    const unsigned short* __restrict__ gi, ull* __restrict__ hxf, ull* __restrict__ hxb) {
    int wgid = blockIdx.x;
    int dir = wgid >> 6;
    int g = wgid & 63;
    const float* whh = dir ? whhb : whhf;
    const float* bhh = dir ? bhhb : bhhf;
    ull* hx = dir ? hxb : hxf;

    int tid = threadIdx.x;
    int kp = tid & 7;
    int q = tid >> 3;            // 0..63
    int kg = g * OPW + kp;
    int wave = tid >> 6;
    int lane = tid & 63;

    // persistent weights
    float4 wr[2], wz[2], wn[2];
    {
        const float4* pr_ = (const float4*)(whh + (size_t)kg * H_DIM + q * 8);
        const float4* pz_ = (const float4*)(whh + (size_t)(kg + 512) * H_DIM + q * 8);
        const float4* pn_ = (const float4*)(whh + (size_t)(kg + 1024) * H_DIM + q * 8);
        wr[0] = pr_[0]; wr[1] = pr_[1];
        wz[0] = pz_[0]; wz[1] = pz_[1];
        wn[0] = pn_[0]; wn[1] = pn_[1];
    }
    float bias_r = 0.f, bias_z = 0.f, bias_n = 0.f, h_own = 0.f;
    int kg0 = g * OPW + lane;    // valid for wave==0 && lane<8
    if (wave == 0 && lane < OPW) {
        bias_r = bhh[kg0]; bias_z = bhh[kg0 + 512]; bias_n = bhh[kg0 + 1024];
    }

    __shared__ float hsh[512];
    __shared__ float part[3][8][OPW];
    hsh[tid] = 0.f;   // h_{-1} = 0
    __syncthreads();

    float gir = 0.f, giz = 0.f, gin = 0.f;

    for (int s = 0; s < T_LEN; s++) {
        int row = dir ? (T_LEN - 1 - s) : s;
        if (wave == 0) {
            // gi loads issued first — in flight during the poll
            if (lane < OPW) {
                const unsigned short* gp = gi + (size_t)row * NG + dir * 1536 + kg0;
                gir = bf2f(gp[0]); giz = bf2f(gp[512]); gin = bf2f(gp[1024]);
            }
            if (s > 0) {
                int prow = dir ? (T_LEN - s) : (s - 1);
                const ull* rowp = hx + (size_t)prow * H_DIM;
                ull v[8];
                bool ok;
                do {
#pragma unroll
                    for (int i = 0; i < 8; i++)
                        v[i] = __hip_atomic_load(rowp + lane + 64 * i,
                                                 __ATOMIC_RELAXED, __HIP_MEMORY_SCOPE_AGENT);
                    ok = true;
#pragma unroll
                    for (int i = 0; i < 8; i++)
                        ok = ok && ((unsigned)(v[i] >> 32) == (unsigned)s);
                } while (!ok);
#pragma unroll
                for (int i = 0; i < 8; i++)
                    hsh[lane + 64 * i] = __uint_as_float((unsigned)v[i]);
            }
        }
        __syncthreads();   // hsh ready

        float4 h0 = *(const float4*)&hsh[q * 8];
        float4 h1 = *(const float4*)&hsh[q * 8 + 4];
        float pr, pz, pn;
        pr  = wr[0].x * h0.x + wr[0].y * h0.y + wr[0].z * h0.z + wr[0].w * h0.w
            + wr[1].x * h1.x + wr[1].y * h1.y + wr[1].z * h1.z + wr[1].w * h1.w;
        pz  = wz[0].x * h0.x + wz[0].y * h0.y + wz[0].z * h0.z + wz[0].w * h0.w
            + wz[1].x * h1.x + wz[1].y * h1.y + wz[1].z * h1.z + wz[1].w * h1.w;
        pn  = wn[0].x * h0.x + wn[0].y * h0.y + wn[0].z * h0.z + wn[0].w * h0.w
            + wn[1].x * h1.x + wn[1].y * h1.y + wn[1].z * h1.z + wn[1].w * h1.w;
        // reduce across q within the wave (lane bits 3..5)
        pr += __shfl_xor(pr, 8);  pz += __shfl_xor(pz, 8);  pn += __shfl_xor(pn, 8);
        pr += __shfl_xor(pr, 16); pz += __shfl_xor(pz, 16); pn += __shfl_xor(pn, 16);
        pr += __shfl_xor(pr, 32); pz += __shfl_xor(pz, 32); pn += __shfl_xor(pn, 32);
        if (lane < OPW) {
            part[0][wave][lane] = pr; part[1][wave][lane] = pz; part[2][wave][lane] = pn;
        }
        __syncthreads();   // parts ready

        if (wave == 0 && lane < OPW) {
            float sr = bias_r, sz = bias_z, sn = bias_n;
#pragma unroll
            for (int w = 0; w < 8; w++) {
                sr += part[0][w][lane]; sz += part[1][w][lane]; sn += part[2][w][lane];
            }
            float rr = 1.f / (1.f + __expf(-(gir + sr)));
            float zz = 1.f / (1.f + __expf(-(giz + sz)));
            float a = gin + rr * sn;
            a = fminf(20.f, fmaxf(-20.f, a));
            float e = __expf(-2.f * a);
            float nn = (1.f - e) / (1.f + e);
            float hnew = (1.f - zz) * nn + zz * h_own;
            h_own = hnew;
            __hip_atomic_store(hx + (size_t)row * H_DIM + kg0, packhs(hnew, (unsigned)(s + 1)),
                               __ATOMIC_RELAXED, __HIP_MEMORY_SCOPE_AGENT);
        }
        // hsh for next step is rewritten only by wave 0 AFTER it passes the
        // parts barrier; all other waves' hsh reads for this step precede it.
    }
}

// ---------- kernel 5: out = [hf|hb] @ W_out^T   [4096 x 32] ----------
__global__ __launch_bounds__(256) void out_gemm(const ull* __restrict__ hxf,
                                                const ull* __restrict__ hxb,
                                                const float* __restrict__ wout,
                                                float* __restrict__ out) {
    __shared__ __align__(16) float ls[8][1028];
    int t0 = blockIdx.x * 8;
    int tid = threadIdx.x;
#pragma unroll
    for (int i = 0; i < 8; i++) {
        int col = tid * 4;   // 0..1020
        const ull* src = (col < 512) ? (hxf + (size_t)(t0 + i) * H_DIM + col)
                                     : (hxb + (size_t)(t0 + i) * H_DIM + (col - 512));
        ull s0 = src[0], s1 = src[1], s2 = src[2], s3 = src[3];
        ls[i][col + 0] = __uint_as_float((unsigned)s0);
        ls[i][col + 1] = __uint_as_float((unsigned)s1);
        ls[i][col + 2] = __uint_as_float((unsigned)s2);
        ls[i][col + 3] = __uint_as_float((unsigned)s3);
    }
    __syncthreads();
    int r8 = tid >> 5, gg = tid & 31;
    const float4* wp = (const float4*)(wout + (size_t)gg * 1024);
    float sum = 0.f;
#pragma unroll 8
    for (int j = 0; j < 256; j++) {
        float4 w = wp[j];
        float4 h = *(const float4*)&ls[r8][j * 4];
        sum += w.x * h.x + w.y * h.y + w.z * h.z + w.w * h.w;
    }
    out[(size_t)(t0 + r8) * NT_DIM + gg] = sum;
}

extern "C" void kernel_launch(void* const* d_in, const int* in_sizes, int n_in,
                              void* d_out, int out_size, void* d_ws, size_t ws_size,
                              hipStream_t stream) {
    const int*   sent = (const int*)d_in[0];
    const float* emb  = (const float*)d_in[1];
    const float* wihf = (const float*)d_in[2];
    const float* whhf = (const float*)d_in[3];
    const float* bihf = (const float*)d_in[4];
    const float* bhhf = (const float*)d_in[5];
    const float* wihb = (const float*)d_in[6];
    const float* whhb = (const float*)d_in[7];
    const float* bihb = (const float*)d_in[8];
    const float* bhhb = (const float*)d_in[9];
    const float* wout = (const float*)d_in[10];

    char* ws = (char*)d_ws;
    unsigned short* gi  = (unsigned short*)(ws);              // 4096*3072*2 = 25165824
    unsigned short* xb  = (unsigned short*)(ws + 25165824);   // 4096*1024*2 =  8388608
    unsigned short* wb  = (unsigned short*)(ws + 33554432);   // 3072*1024*2 =  6291456
    ull*            hxf = (ull*)(ws + 39845888);              // 4096*512*8  = 16777216
    ull*            hxb = (ull*)(ws + 56623104);              // 16777216 (total 73400320)
    float*          out = (float*)d_out;

    embed_cast<<<T_LEN, 256, 0, stream>>>(sent, emb, xb);
    wcast<<<NG, 256, 0, stream>>>(wihf, wihb, wb);
    gi_gemm<<<64 * 48, 256, 0, stream>>>(xb, wb, bihf, bihb, gi);
    gru_rec<<<2 * G_DIR, 512, 0, stream>>>(whhf, bhhf, whhb, bhhb, gi, hxf, hxb);
    out_gemm<<<T_LEN / 8, 256, 0, stream>>>(hxf, hxb, wout, out);
}